// Round 2
// baseline (482.603 us; speedup 1.0000x reference)
//
#include <hip/hip_runtime.h>

// BitPredictor: scalar LSTM (hidden=1) iterated FEATURES times; output is one
// 512-float row broadcast across the 65536-row batch (no per-batch input, all
// carries start at zero => batch dimension is degenerate).
#define FEATURES 512

__device__ __forceinline__ float sigm(float v) {
    return 1.0f / (1.0f + __expf(-v));
}
__device__ __forceinline__ float tanh_fast(float v) {
    float e = __expf(-2.0f * v);
    return (1.0f - e) / (1.0f + e);
}

// 2048 blocks x 256 threads = 524288 threads (exactly one resident wave of
// blocks on 256 CUs: 8 blocks/CU x 4 waves = 32 waves/CU). Thread 0 of each
// block redundantly computes the 512-step recurrence into LDS (~13us of pure
// serial latency, but wall-clock-parallel across all co-resident blocks),
// then every thread streams pure float4 stores.
__global__ __launch_bounds__(256) void bitpred_kernel(
    const float* __restrict__ Wi, const float* __restrict__ Wh,
    const float* __restrict__ b, float* __restrict__ out,
    long long total4)
{
    __shared__ float4 hrow[FEATURES / 4];

    if (threadIdx.x == 0) {
        const float wi0 = Wi[0], wi1 = Wi[1], wi2 = Wi[2], wi3 = Wi[3];
        const float wh0 = Wh[0], wh1 = Wh[1], wh2 = Wh[2], wh3 = Wh[3];
        const float b0 = b[0], b1 = b[1], b2 = b[2], b3 = b[3];
        float c = 0.f, h = 0.f, x = 0.f;
        float* hs = (float*)hrow;
        for (int t = 0; t < FEATURES; ++t) {
            // gate order from jnp.split: i, f, g, o
            float gi = fmaf(x, wi0, fmaf(h, wh0, b0));
            float gf = fmaf(x, wi1, fmaf(h, wh1, b1));
            float gg = fmaf(x, wi2, fmaf(h, wh2, b2));
            float go = fmaf(x, wi3, fmaf(h, wh3, b3));
            c = sigm(gf) * c + sigm(gi) * tanh_fast(gg);
            h = sigm(go) * tanh_fast(c);
            x = h;  // carry feeds h back as next input
            hs[t] = h;
        }
    }
    __syncthreads();

    const long long stride = (long long)gridDim.x * blockDim.x;  // 524288
    long long gid = (long long)blockIdx.x * blockDim.x + threadIdx.x;
    // stride % (FEATURES/4) == 0 => each thread's column chunk is invariant:
    // load its float4 of the row once, then issue pure stores.
    const float4 val = hrow[gid & (FEATURES / 4 - 1)];
    float4* __restrict__ out4 = (float4*)out;
    for (long long i = gid; i < total4; i += stride) {
        out4[i] = val;
    }
}

extern "C" void kernel_launch(void* const* d_in, const int* in_sizes, int n_in,
                              void* d_out, int out_size, void* d_ws, size_t ws_size,
                              hipStream_t stream) {
    // setup_inputs order: batch_size (int scalar), Wi (4 f32), Wh (4 f32), b (4 f32)
    const float* Wi = (const float*)d_in[1];
    const float* Wh = (const float*)d_in[2];
    const float* b  = (const float*)d_in[3];
    float* out = (float*)d_out;

    long long total4 = (long long)out_size / 4;  // 8,388,608 float4s (128 MiB)
    hipLaunchKernelGGL(bitpred_kernel, dim3(2048), dim3(256), 0, stream,
                       Wi, Wh, b, out, total4);
}

// Round 7
// 144.860 us; speedup vs baseline: 3.3315x; 3.3315x over previous
//
#include <hip/hip_runtime.h>

// BitPredictor: scalar LSTM (hidden=1) iterated FEATURES times; output is one
// 512-float row broadcast across the 65536-row batch (batch dim degenerate:
// zero init carry, no per-batch input).
//
// R2 lesson (rocprof): WRITE_SIZE was exactly 128 MiB and hbm_pct_peak only
// 4.4%, VALUBusy 42% -> the 380us was the single-lane serial recurrence
// (IEEE div chains, ~1000 cy/step), NOT the stores. Fix: fixed-point early
// exit (this input hits the (0,0) fixed point after 1 step) + rcp/exp2-based
// gates for the general path.
#define FEATURES 512

__device__ __forceinline__ float fast_sigm(float v) {
    // 1/(1+exp(-v)) via native exp2 + rcp (v_exp_f32, v_rcp_f32)
    const float L2E = 1.44269504f;
    float e = __builtin_amdgcn_exp2f(-L2E * v);
    return __builtin_amdgcn_rcpf(1.0f + e);
}
__device__ __forceinline__ float fast_tanh(float v) {
    // tanh(v) = 1 - 2/(exp2(2*log2e*v)+1)
    const float L2E2 = 2.88539008f;
    float e = __builtin_amdgcn_exp2f(L2E2 * v);
    return 1.0f - 2.0f * __builtin_amdgcn_rcpf(e + 1.0f);
}

// 2048 blocks x 256 threads = 524288 threads (8 blocks/CU x 4 waves = full
// residency on 256 CUs). Thread 0 of each block computes the recurrence into
// LDS (early-exits at the bitwise fixed point), then all threads stream
// float4 stores (identical store loop to R2 for clean phase attribution).
__global__ __launch_bounds__(256) void bitpred_kernel(
    const float* __restrict__ Wi, const float* __restrict__ Wh,
    const float* __restrict__ b, float* __restrict__ out,
    long long total4)
{
    __shared__ float4 hrow[FEATURES / 4];

    if (threadIdx.x == 0) {
        // x == h invariant (x0 = h0 = 0, x_{t+1} = h_{t+1}) => gates use Wi+Wh.
        const float w0 = Wi[0] + Wh[0], w1 = Wi[1] + Wh[1];
        const float w2 = Wi[2] + Wh[2], w3 = Wi[3] + Wh[3];
        const float b0 = b[0], b1 = b[1], b2 = b[2], b3 = b[3];
        float c = 0.f, h = 0.f;
        float pc = 0.f, ph = 0.f;  // previous state (c0, h0)
        float* hs = (float*)hrow;
        int t = 0;
        for (; t < FEATURES; ++t) {
            // gate order from jnp.split: i, f, g, o
            float gi = fmaf(h, w0, b0);
            float gf = fmaf(h, w1, b1);
            float gg = fmaf(h, w2, b2);
            float go = fmaf(h, w3, b3);
            c = fast_sigm(gf) * c + fast_sigm(gi) * fast_tanh(gg);
            h = fast_sigm(go) * fast_tanh(c);
            hs[t] = h;
            // Bitwise fixed point: state equals previous state => every
            // subsequent h is identical. (b=0 input: true at t=0.)
            if (c == pc && h == ph) break;
            pc = c; ph = h;
        }
        // Fill the remainder of the row with the fixed-point h.
        const float hf = h;
        for (int k = t + 1; k < FEATURES; ++k) hs[k] = hf;
    }
    __syncthreads();

    const long long stride = (long long)gridDim.x * blockDim.x;  // 524288
    long long gid = (long long)blockIdx.x * blockDim.x + threadIdx.x;
    // stride % (FEATURES/4) == 0 => each thread's column chunk is invariant:
    // load its float4 of the row once, then issue pure coalesced stores.
    const float4 val = hrow[gid & (FEATURES / 4 - 1)];
    float4* __restrict__ out4 = (float4*)out;
    for (long long i = gid; i < total4; i += stride) {
        out4[i] = val;
    }
}

extern "C" void kernel_launch(void* const* d_in, const int* in_sizes, int n_in,
                              void* d_out, int out_size, void* d_ws, size_t ws_size,
                              hipStream_t stream) {
    // setup_inputs order: batch_size (int scalar), Wi (4 f32), Wh (4 f32), b (4 f32)
    const float* Wi = (const float*)d_in[1];
    const float* Wh = (const float*)d_in[2];
    const float* b  = (const float*)d_in[3];
    float* out = (float*)d_out;

    long long total4 = (long long)out_size / 4;  // 8,388,608 float4s (128 MiB)
    hipLaunchKernelGGL(bitpred_kernel, dim3(2048), dim3(256), 0, stream,
                       Wi, Wh, b, out, total4);
}

// Round 9
// 142.801 us; speedup vs baseline: 3.3796x; 1.0144x over previous
//
#include <hip/hip_runtime.h>

// BitPredictor: scalar LSTM (hidden=1) iterated FEATURES times; output is one
// 512-float row broadcast across the 65536-row batch (batch dim degenerate).
//
// R2 lesson: 380us was the single-lane serial recurrence (IEEE div chains),
// not the stores -> fixed-point early exit + exp2/rcp gates (R7: 44us kernel).
// R7 lesson: harness poison fills hit 6.6 TB/s (83% peak) in the SAME graph,
// while our store phase ran ~3.0 TB/s. Theory: 8MiB grid-stride = one fresh
// HBM row per 1KB burst (row-buffer thrash). Fix: each wave owns a contiguous
// 16KB segment (8192 waves x 16KB = 128MiB exactly), sequential bursts.
#define FEATURES 512

__device__ __forceinline__ float fast_sigm(float v) {
    const float L2E = 1.44269504f;
    float e = __builtin_amdgcn_exp2f(-L2E * v);
    return __builtin_amdgcn_rcpf(1.0f + e);
}
__device__ __forceinline__ float fast_tanh(float v) {
    const float L2E2 = 2.88539008f;
    float e = __builtin_amdgcn_exp2f(L2E2 * v);
    return 1.0f - 2.0f * __builtin_amdgcn_rcpf(e + 1.0f);
}

// 2048 blocks x 256 threads; thread 0 of each block computes the recurrence
// into LDS (bitwise fixed-point early exit), then each of the block's 4 waves
// streams one contiguous 16KB segment as float4 stores.
__global__ __launch_bounds__(256) void bitpred_kernel(
    const float* __restrict__ Wi, const float* __restrict__ Wh,
    const float* __restrict__ b, float* __restrict__ out,
    long long total4)
{
    __shared__ float hrow[FEATURES];

    if (threadIdx.x == 0) {
        // x == h invariant (x0 = h0 = 0, x_{t+1} = h_{t+1}) => gates use Wi+Wh.
        const float w0 = Wi[0] + Wh[0], w1 = Wi[1] + Wh[1];
        const float w2 = Wi[2] + Wh[2], w3 = Wi[3] + Wh[3];
        const float b0 = b[0], b1 = b[1], b2 = b[2], b3 = b[3];
        float c = 0.f, h = 0.f;
        float pc = 0.f, ph = 0.f;
        int t = 0;
        for (; t < FEATURES; ++t) {
            // gate order from jnp.split: i, f, g, o
            float gi = fmaf(h, w0, b0);
            float gf = fmaf(h, w1, b1);
            float gg = fmaf(h, w2, b2);
            float go = fmaf(h, w3, b3);
            c = fast_sigm(gf) * c + fast_sigm(gi) * fast_tanh(gg);
            h = fast_sigm(go) * fast_tanh(c);
            hrow[t] = h;
            // Bitwise fixed point => all subsequent h identical. (b=0: t=0.)
            if (c == pc && h == ph) break;
            pc = c; ph = h;
        }
        const float hf = h;
        for (int k = t + 1; k < FEATURES; ++k) hrow[k] = hf;
    }
    __syncthreads();

    // Wave-contiguous store plan: wave g owns float4s [g*1024, (g+1)*1024).
    // 1024 % 128 == 0, so lane l needs only row float4s l and l+64,
    // alternating per 1KB burst. 16 bursts x 1KB = 16KB contiguous per wave.
    const int lane = threadIdx.x & 63;
    const long long wave_g = (long long)blockIdx.x * 4 + (threadIdx.x >> 6);
    const long long base4 = wave_g * 1024;  // float4 units
    const float4* hrow4 = (const float4*)hrow;
    const float4 v0 = hrow4[lane];
    const float4 v1 = hrow4[lane + 64];
    float4* __restrict__ out4 = (float4*)out;
    if (base4 < total4) {
#pragma unroll
        for (int it = 0; it < 16; it += 2) {
            out4[base4 + it * 64 + lane] = v0;
            out4[base4 + (it + 1) * 64 + lane] = v1;
        }
    }
}

extern "C" void kernel_launch(void* const* d_in, const int* in_sizes, int n_in,
                              void* d_out, int out_size, void* d_ws, size_t ws_size,
                              hipStream_t stream) {
    // setup_inputs order: batch_size (int scalar), Wi (4 f32), Wh (4 f32), b (4 f32)
    const float* Wi = (const float*)d_in[1];
    const float* Wh = (const float*)d_in[2];
    const float* b  = (const float*)d_in[3];
    float* out = (float*)d_out;

    long long total4 = (long long)out_size / 4;  // 8,388,608 float4s (128 MiB)
    hipLaunchKernelGGL(bitpred_kernel, dim3(2048), dim3(256), 0, stream,
                       Wi, Wh, b, out, total4);
}

// Round 11
// 137.919 us; speedup vs baseline: 3.4992x; 1.0354x over previous
//
#include <hip/hip_runtime.h>

// BitPredictor: scalar LSTM (hidden=1) iterated FEATURES times; output is one
// 512-float row broadcast across the 65536-row batch (batch dim degenerate).
//
// R2: 380us = single-lane serial recurrence (IEEE div chains) -> fixed-point
//     early exit + exp2/rcp gates. Kernel now ~40us.
// R7/R9: two opposite store layouts (8MiB grid-stride vs contiguous 16KB/wave)
//     BOTH run ~3.2 TB/s while the harness fill hits 6.6 TB/s in the same
//     graph -> address pattern exonerated. Fill runs at 9.6% occupancy with
//     long-lived waves; we ran 8192 short-lived waves x 16 stores (one-shot
//     burst + mass drain). R10 experiment: fill-like structure - 512 blocks
//     (8 waves/CU), 64 contiguous stores per thread, long-lived waves.
#define FEATURES 512

__device__ __forceinline__ float fast_sigm(float v) {
    const float L2E = 1.44269504f;
    float e = __builtin_amdgcn_exp2f(-L2E * v);
    return __builtin_amdgcn_rcpf(1.0f + e);
}
__device__ __forceinline__ float fast_tanh(float v) {
    const float L2E2 = 2.88539008f;
    float e = __builtin_amdgcn_exp2f(L2E2 * v);
    return 1.0f - 2.0f * __builtin_amdgcn_rcpf(e + 1.0f);
}

// 512 blocks x 256 threads = 2048 waves; each wave owns one contiguous 64KB
// segment (2048 x 64KB = 128MiB exactly). Thread 0 computes the recurrence
// (bitwise fixed-point early exit); remainder of the row is filled in
// parallel by all 256 threads.
__global__ __launch_bounds__(256) void bitpred_kernel(
    const float* __restrict__ Wi, const float* __restrict__ Wh,
    const float* __restrict__ b, float* __restrict__ out,
    long long total4)
{
    __shared__ float hrow[FEATURES];
    __shared__ float s_hf;
    __shared__ int s_t;

    if (threadIdx.x == 0) {
        // x == h invariant (x0 = h0 = 0, x_{t+1} = h_{t+1}) => gates use Wi+Wh.
        const float w0 = Wi[0] + Wh[0], w1 = Wi[1] + Wh[1];
        const float w2 = Wi[2] + Wh[2], w3 = Wi[3] + Wh[3];
        const float b0 = b[0], b1 = b[1], b2 = b[2], b3 = b[3];
        float c = 0.f, h = 0.f;
        float pc = 0.f, ph = 0.f;
        int t = 0;
        for (; t < FEATURES; ++t) {
            // gate order from jnp.split: i, f, g, o
            float gi = fmaf(h, w0, b0);
            float gf = fmaf(h, w1, b1);
            float gg = fmaf(h, w2, b2);
            float go = fmaf(h, w3, b3);
            c = fast_sigm(gf) * c + fast_sigm(gi) * fast_tanh(gg);
            h = fast_sigm(go) * fast_tanh(c);
            hrow[t] = h;
            // Bitwise fixed point => all subsequent h identical. (b=0: t=0.)
            if (c == pc && h == ph) break;
            pc = c; ph = h;
        }
        s_hf = h;
        s_t = t;
    }
    __syncthreads();
    // Parallel remainder fill (was a 511-iter single-lane loop, ~2us).
    {
        const float hf = s_hf;
        for (int k = s_t + 1 + (int)threadIdx.x; k < FEATURES; k += 256)
            hrow[k] = hf;
    }
    __syncthreads();

    // Wave g owns float4s [g*4096, (g+1)*4096) = 64KB contiguous.
    // 4096 % 128 == 0: lane l only ever writes row float4s l and l+64,
    // alternating per 1KB burst. 64 bursts per wave, long-lived waves.
    const int lane = threadIdx.x & 63;
    const long long wave_g = (long long)blockIdx.x * 4 + (threadIdx.x >> 6);
    const long long base4 = wave_g * 4096;  // float4 units
    const float4* hrow4 = (const float4*)hrow;
    const float4 v0 = hrow4[lane];
    const float4 v1 = hrow4[lane + 64];
    float4* __restrict__ out4 = (float4*)out;
    if (base4 < total4) {
#pragma unroll 8
        for (int it = 0; it < 64; it += 2) {
            out4[base4 + it * 64 + lane] = v0;
            out4[base4 + (it + 1) * 64 + lane] = v1;
        }
    }
}

extern "C" void kernel_launch(void* const* d_in, const int* in_sizes, int n_in,
                              void* d_out, int out_size, void* d_ws, size_t ws_size,
                              hipStream_t stream) {
    // setup_inputs order: batch_size (int scalar), Wi (4 f32), Wh (4 f32), b (4 f32)
    const float* Wi = (const float*)d_in[1];
    const float* Wh = (const float*)d_in[2];
    const float* b  = (const float*)d_in[3];
    float* out = (float*)d_out;

    long long total4 = (long long)out_size / 4;  // 8,388,608 float4s (128 MiB)
    hipLaunchKernelGGL(bitpred_kernel, dim3(512), dim3(256), 0, stream,
                       Wi, Wh, b, out, total4);
}